// Round 1
// baseline (334.601 us; speedup 1.0000x reference)
//
#include <hip/hip_runtime.h>
#include <hip/hip_bf16.h>

#define N_NODES    50000
#define DIM        128
#define NUM_GRAPHS 64
#define NUM_CLASSES 3
#define NPAD       50176   // 196*256
#define XPITCH     136     // LDS row pitch in ushorts (17 x 16B, odd -> conflict-free b128)

typedef unsigned short ushort_t;
typedef unsigned int   uint_t;
typedef __attribute__((ext_vector_type(8))) short short8;
typedef __attribute__((ext_vector_type(4))) float f32x4;

__device__ __forceinline__ ushort_t f2bf(float f) {
    union { float f; uint_t u; } v; v.f = f;
    uint_t r = v.u + 0x7fffu + ((v.u >> 16) & 1u);   // RNE
    return (ushort_t)(r >> 16);
}
__device__ __forceinline__ float bflo(uint_t u) {
    union { uint_t u; float f; } v; v.u = u << 16; return v.f;
}
__device__ __forceinline__ float bfhi(uint_t u) {
    union { uint_t u; float f; } v; v.u = u & 0xffff0000u; return v.f;
}

__device__ __forceinline__ void accum8(float* a, uint4 u) {
    a[0] += bflo(u.x); a[1] += bfhi(u.x);
    a[2] += bflo(u.y); a[3] += bfhi(u.y);
    a[4] += bflo(u.z); a[5] += bfhi(u.z);
    a[6] += bflo(u.w); a[7] += bfhi(u.w);
}

// Wide gather: 16 lanes per edge (subgroup g = lane>>4 handles edge p+g,
// lane c = lane&15 holds channels c*8..c*8+7 as one uint4 = dwordx4 load).
// One load instruction covers 4 edges (1KB); 4-batch double buffer keeps
// 16 edges (4KB) in flight per wave. Caller must shfl_xor(16,32)-reduce
// the per-subgroup partials and add the self-loop row afterwards.
__device__ __forceinline__ void gather_x4(
    int n, int g, int c, const int* __restrict__ rowptr,
    const int* __restrict__ csr_src, const uint4* __restrict__ Tb4,
    float* a)
{
    int p0 = rowptr[n], p1 = rowptr[n + 1];
    int p = p0;
    int nb = (p1 - p0) >> 2;            // full 4-edge batches
    int ng = nb >> 2;                   // 16-edge groups
    if (ng > 0) {
        uint4 cur[4];
        int s0[4];
        #pragma unroll
        for (int d = 0; d < 4; ++d) s0[d] = csr_src[p + 4 * d + g];
        #pragma unroll
        for (int d = 0; d < 4; ++d) cur[d] = Tb4[s0[d] * 16 + c];
        for (int b = 1; b < ng; ++b) {
            uint4 nxt[4];
            int s1[4];
            #pragma unroll
            for (int d = 0; d < 4; ++d) s1[d] = csr_src[p + 16 + 4 * d + g];
            #pragma unroll
            for (int d = 0; d < 4; ++d) nxt[d] = Tb4[s1[d] * 16 + c];
            #pragma unroll
            for (int d = 0; d < 4; ++d) accum8(a, cur[d]);
            #pragma unroll
            for (int d = 0; d < 4; ++d) cur[d] = nxt[d];
            p += 16;
        }
        #pragma unroll
        for (int d = 0; d < 4; ++d) accum8(a, cur[d]);
        p += 16;
    }
    // remaining full 4-edge batches (0..3)
    for (; p + 4 <= p1; p += 4) {
        int s = csr_src[p + g];
        uint4 u = Tb4[s * 16 + c];
        accum8(a, u);
    }
    // tail 0..3 edges: subgroups g < rem participate
    if (p + g < p1) {
        int s = csr_src[p + g];
        uint4 u = Tb4[s * 16 + c];
        accum8(a, u);
    }
}

// ---------------- init ----------------
__global__ void k_init(int* degi, float* pooled, float* counts) {
    int i = blockIdx.x * 256 + threadIdx.x;
    if (i < NPAD) degi[i] = 0;
    if (i < NUM_GRAPHS * DIM) pooled[i] = 0.0f;
    if (i < NUM_GRAPHS) counts[i] = 0.0f;
}

// ---------------- W -> Wt bf16 transpose (all 3 layers) ----------------
__global__ void k_prep(const float* __restrict__ W1, const float* __restrict__ W2,
                       const float* __restrict__ W3, ushort_t* __restrict__ Wt) {
    int i = blockIdx.x * 256 + threadIdx.x;
    int mat = i >> 14;
    int idx = i & 16383;
    const float* W = (mat == 0) ? W1 : (mat == 1) ? W2 : W3;
    int n = idx >> 7, k = idx & 127;
    Wt[mat * 16384 + n * 128 + k] = f2bf(W[k * 128 + n]);
}

// ---------------- degree histogram; atomic return = within-row rank ----------------
__global__ void k_count(const int* __restrict__ dst, int* degi, int* rank, int nedges) {
    int e = blockIdx.x * 256 + threadIdx.x;
    if (e < nedges) rank[e] = atomicAdd(&degi[dst[e]], 1);
}

// ---------------- scan ----------------
__global__ __launch_bounds__(256) void k_scan1(const int* __restrict__ degi,
                                               int* rowptr, int* bsum) {
    __shared__ int sh[256];
    int i = blockIdx.x * 256 + threadIdx.x;
    int v = degi[i];
    sh[threadIdx.x] = v;
    __syncthreads();
    for (int off = 1; off < 256; off <<= 1) {
        int t = (threadIdx.x >= off) ? sh[threadIdx.x - off] : 0;
        __syncthreads();
        sh[threadIdx.x] += t;
        __syncthreads();
    }
    rowptr[i] = sh[threadIdx.x] - v;
    if (threadIdx.x == 255) bsum[blockIdx.x] = sh[255];
}

__global__ __launch_bounds__(256) void k_scan2(int* bsum, int nblocks) {
    __shared__ int sh[256];
    int v = (threadIdx.x < nblocks) ? bsum[threadIdx.x] : 0;
    sh[threadIdx.x] = v;
    __syncthreads();
    for (int off = 1; off < 256; off <<= 1) {
        int t = (threadIdx.x >= off) ? sh[threadIdx.x - off] : 0;
        __syncthreads();
        sh[threadIdx.x] += t;
        __syncthreads();
    }
    if (threadIdx.x < nblocks) bsum[threadIdx.x] = sh[threadIdx.x] - v;
}

__global__ __launch_bounds__(256) void k_scan3(int* rowptr, const int* __restrict__ bsum,
                                               const int* __restrict__ degi,
                                               float* dinv) {
    int i = blockIdx.x * 256 + threadIdx.x;
    rowptr[i] = rowptr[i] + bsum[blockIdx.x];
    if (i < N_NODES) dinv[i] = rsqrtf((float)degi[i] + 1.0f);
}

// ---------------- CSR fill: atomic-free scatter via precomputed rank ----------------
__global__ void k_fill(const int* __restrict__ src, const int* __restrict__ dst,
                       const int* __restrict__ rank, const int* __restrict__ rowptr,
                       int* csr_src, int nedges) {
    int e = blockIdx.x * 256 + threadIdx.x;
    if (e < nedges) csr_src[rowptr[dst[e]] + rank[e]] = src[e];
}

// ---------------- layer-1 matmul: Tb1' = (x @ W1) * dinv[row] ----------------
__global__ __launch_bounds__(256) void k_mm1(
    const float* __restrict__ xin, const ushort_t* __restrict__ WtG,
    const float* __restrict__ dinv, ushort_t* __restrict__ TbOut)
{
    __shared__ ushort_t Wl[DIM * XPITCH];
    __shared__ ushort_t Xl[64 * XPITCH];

    const int tid = threadIdx.x;
    const int rowbase = blockIdx.x * 64;

    #pragma unroll
    for (int i = 0; i < 8; ++i) {
        int g = tid + i * 256;
        uint4 v = ((const uint4*)WtG)[g];
        *((uint4*)&Wl[(g >> 4) * XPITCH + (g & 15) * 8]) = v;
    }
    #pragma unroll
    for (int i = 0; i < 8; ++i) {
        int c = tid + i * 256;
        int row = c >> 5;
        int grow = rowbase + row;
        float4 f = make_float4(0.f, 0.f, 0.f, 0.f);
        if (grow < N_NODES)
            f = ((const float4*)xin)[(long long)rowbase * 32 + c];
        ushort4 h;
        h.x = f2bf(f.x); h.y = f2bf(f.y); h.z = f2bf(f.z); h.w = f2bf(f.w);
        *((ushort4*)&Xl[row * XPITCH + (c & 31) * 4]) = h;
    }
    __syncthreads();

    const int wave = tid >> 6;
    const int lane = tid & 63;
    const int quad = lane >> 4;
    const int lm   = lane & 15;
    const int m0   = wave * 16;

    short8 af[4];
    #pragma unroll
    for (int k0 = 0; k0 < 4; ++k0)
        af[k0] = *(const short8*)&Xl[(m0 + lm) * XPITCH + k0 * 32 + quad * 8];

    int noder[4]; float di[4]; bool okr[4];
    #pragma unroll
    for (int r = 0; r < 4; ++r) {
        noder[r] = rowbase + m0 + quad * 4 + r;
        okr[r] = (noder[r] < N_NODES);
        di[r] = okr[r] ? dinv[noder[r]] : 0.f;
    }

    for (int n0 = 0; n0 < DIM; n0 += 16) {
        f32x4 acc = {0.f, 0.f, 0.f, 0.f};
        #pragma unroll
        for (int k0 = 0; k0 < 4; ++k0) {
            short8 bf = *(const short8*)&Wl[(n0 + lm) * XPITCH + k0 * 32 + quad * 8];
            acc = __builtin_amdgcn_mfma_f32_16x16x32_bf16(af[k0], bf, acc, 0, 0, 0);
        }
        int n = n0 + lm;
        #pragma unroll
        for (int r = 0; r < 4; ++r)
            if (okr[r])
                TbOut[(long long)noder[r] * DIM + n] = f2bf(acc[r] * di[r]);
    }
}

// ---------------- fused: X = ReLU(b + dinv[n]*Sum Tb'[s]) ; Tb_out' = (X@W)*dinv ----------------
__global__ __launch_bounds__(256) void k_fused(
    const int* __restrict__ rowptr, const int* __restrict__ csr_src,
    const float* __restrict__ dinv, const uint_t* __restrict__ TbIn,
    const ushort_t* __restrict__ WtG, const float* __restrict__ b_prev,
    ushort_t* __restrict__ TbOut)
{
    __shared__ ushort_t Xl[16 * XPITCH];   // 4352 B

    const int tid = threadIdx.x;
    const int rowbase = blockIdx.x * 16;
    const int wave = tid >> 6;
    const int lane = tid & 63;
    const int g    = lane >> 4;    // edge subgroup
    const int c    = lane & 15;    // channel-group: ch c*8..c*8+7
    const uint4* Tb4 = (const uint4*)TbIn;

    float4 blo = ((const float4*)b_prev)[c * 2];
    float4 bhi = ((const float4*)b_prev)[c * 2 + 1];

    #pragma unroll
    for (int t = 0; t < 4; ++t) {
        int r = wave * 4 + t;
        int n = rowbase + r;
        float a[8] = {0.f, 0.f, 0.f, 0.f, 0.f, 0.f, 0.f, 0.f};
        float dd = 0.f;
        uint4 uself = make_uint4(0u, 0u, 0u, 0u);
        if (n < N_NODES) {
            uself = Tb4[n * 16 + c];     // self loop (issue early)
            dd = dinv[n];
            gather_x4(n, g, c, rowptr, csr_src, Tb4, a);
        }
        // reduce the 4 subgroup partials (lanes c, c+16, c+32, c+48)
        #pragma unroll
        for (int i = 0; i < 8; ++i) {
            a[i] += __shfl_xor(a[i], 16);
            a[i] += __shfl_xor(a[i], 32);
        }
        accum8(a, uself);                // self added exactly once (post-reduce)
        if (g == 0) {
            short8 h;
            h[0] = (short)f2bf(fmaxf(blo.x + a[0] * dd, 0.f));
            h[1] = (short)f2bf(fmaxf(blo.y + a[1] * dd, 0.f));
            h[2] = (short)f2bf(fmaxf(blo.z + a[2] * dd, 0.f));
            h[3] = (short)f2bf(fmaxf(blo.w + a[3] * dd, 0.f));
            h[4] = (short)f2bf(fmaxf(bhi.x + a[4] * dd, 0.f));
            h[5] = (short)f2bf(fmaxf(bhi.y + a[5] * dd, 0.f));
            h[6] = (short)f2bf(fmaxf(bhi.z + a[6] * dd, 0.f));
            h[7] = (short)f2bf(fmaxf(bhi.w + a[7] * dd, 0.f));
            *((short8*)&Xl[r * XPITCH + c * 8]) = h;
        }
    }
    __syncthreads();

    const int quad = lane >> 4;
    const int lm   = lane & 15;

    short8 af[4];
    #pragma unroll
    for (int k0 = 0; k0 < 4; ++k0)
        af[k0] = *(const short8*)&Xl[lm * XPITCH + k0 * 32 + quad * 8];

    int noder[4]; float di[4]; bool okr[4];
    #pragma unroll
    for (int r = 0; r < 4; ++r) {
        noder[r] = rowbase + quad * 4 + r;
        okr[r] = (noder[r] < N_NODES);
        di[r] = okr[r] ? dinv[noder[r]] : 0.f;
    }

    #pragma unroll
    for (int h = 0; h < 2; ++h) {
        int n0 = wave * 32 + h * 16;
        f32x4 acc = {0.f, 0.f, 0.f, 0.f};
        #pragma unroll
        for (int k0 = 0; k0 < 4; ++k0) {
            short8 bf = *(const short8*)&WtG[(n0 + lm) * DIM + k0 * 32 + quad * 8];
            acc = __builtin_amdgcn_mfma_f32_16x16x32_bf16(af[k0], bf, acc, 0, 0, 0);
        }
        int n = n0 + lm;
        #pragma unroll
        for (int r = 0; r < 4; ++r)
            if (okr[r])
                TbOut[(long long)noder[r] * DIM + n] = f2bf(acc[r] * di[r]);
    }
}

// ---------------- fused gather + mean-pool, LDS flush accumulation ----------------
// 8-row strips. Wide gather_x4 core; after the shfl reduce each lane holds the
// full channel-slice sum, and keeps running pacc for its own 2 channels
// (ch = c*8 + 2*g) so the flush atomic pattern is unchanged.
__global__ __launch_bounds__(256) void k_poolgather(
    const int* __restrict__ rowptr, const int* __restrict__ csr_src,
    const float* __restrict__ dinv, const uint_t* __restrict__ Tb,
    const float* __restrict__ b3, const int* __restrict__ batch,
    float* pooled, float* counts)
{
    __shared__ float lp[8][DIM];   // 4 KB
    __shared__ float lc[8];

    const int tid  = threadIdx.x;
    const int wave = tid >> 6;
    const int lane = tid & 63;
    const int g    = lane >> 4;
    const int c    = lane & 15;
    const int blk0 = blockIdx.x * 32;
    const uint4* Tb4 = (const uint4*)Tb;

    #pragma unroll
    for (int i = 0; i < 4; ++i) ((float*)lp)[tid + i * 256] = 0.f;
    if (tid < 8) lc[tid] = 0.f;
    __syncthreads();

    const int gbase = batch[min(blk0, N_NODES - 1)];
    int n0 = blk0 + wave * 8;
    const int ch = c * 8 + 2 * g;      // this lane's 2 output channels

    if (n0 < N_NODES) {
        int nend = min(n0 + 8, N_NODES);
        float4 blo = ((const float4*)b3)[c * 2];
        float4 bhi = ((const float4*)b3)[c * 2 + 1];
        float bb0 = (g == 0) ? blo.x : (g == 1) ? blo.z : (g == 2) ? bhi.x : bhi.z;
        float bb1 = (g == 0) ? blo.y : (g == 1) ? blo.w : (g == 2) ? bhi.y : bhi.w;
        int cur = batch[n0];
        int runstart = n0;
        float pacc0 = 0.f, pacc1 = 0.f;

        for (int n = n0; n < nend; ++n) {
            int gb = batch[n];
            if (gb != cur) {
                int slot = cur - gbase;
                if (slot < 8) {
                    atomicAdd(&lp[slot][ch], pacc0);
                    atomicAdd(&lp[slot][ch + 1], pacc1);
                    if (lane == 0) atomicAdd(&lc[slot], (float)(n - runstart));
                } else {
                    atomicAdd(&pooled[cur * DIM + ch], pacc0);
                    atomicAdd(&pooled[cur * DIM + ch + 1], pacc1);
                    if (lane == 0) atomicAdd(&counts[cur], (float)(n - runstart));
                }
                pacc0 = 0.f; pacc1 = 0.f; cur = gb; runstart = n;
            }
            float a[8] = {0.f, 0.f, 0.f, 0.f, 0.f, 0.f, 0.f, 0.f};
            uint4 uself = Tb4[n * 16 + c];
            gather_x4(n, g, c, rowptr, csr_src, Tb4, a);
            #pragma unroll
            for (int i = 0; i < 8; ++i) {
                a[i] += __shfl_xor(a[i], 16);
                a[i] += __shfl_xor(a[i], 32);
            }
            accum8(a, uself);
            float dd = dinv[n];
            // select this lane's 2 channels (a[2g], a[2g+1])
            float x0 = (g == 0) ? a[0] : (g == 1) ? a[2] : (g == 2) ? a[4] : a[6];
            float x1 = (g == 0) ? a[1] : (g == 1) ? a[3] : (g == 2) ? a[5] : a[7];
            pacc0 += bb0 + x0 * dd;
            pacc1 += bb1 + x1 * dd;
        }
        int slot = cur - gbase;
        if (slot < 8) {
            atomicAdd(&lp[slot][ch], pacc0);
            atomicAdd(&lp[slot][ch + 1], pacc1);
            if (lane == 0) atomicAdd(&lc[slot], (float)(nend - runstart));
        } else {
            atomicAdd(&pooled[cur * DIM + ch], pacc0);
            atomicAdd(&pooled[cur * DIM + ch + 1], pacc1);
            if (lane == 0) atomicAdd(&counts[cur], (float)(nend - runstart));
        }
    }
    __syncthreads();

    #pragma unroll
    for (int s = 0; s < 8; ++s) {
        if (lc[s] != 0.f) {
            if (tid < DIM) atomicAdd(&pooled[(gbase + s) * DIM + tid], lp[s][tid]);
            if (tid == DIM) atomicAdd(&counts[gbase + s], lc[s]);
        }
    }
}

// ---------------- classifier head ----------------
__global__ __launch_bounds__(128) void k_cls(
    const float* __restrict__ pooled, const float* __restrict__ counts,
    const float* __restrict__ C1, const float* __restrict__ bc1,
    const float* __restrict__ C2, const float* __restrict__ bc2,
    float* out)
{
    __shared__ float pm[DIM];
    __shared__ float gv[DIM];
    int g = blockIdx.x, j = threadIdx.x;
    float cnt = fmaxf(counts[g], 1.0f);
    pm[j] = pooled[g * DIM + j] / cnt;
    __syncthreads();
    float a = bc1[j];
    for (int k = 0; k < DIM; ++k) a += pm[k] * C1[k * DIM + j];
    gv[j] = fmaxf(a, 0.f);
    __syncthreads();
    if (j < NUM_CLASSES) {
        float o = bc2[j];
        for (int k = 0; k < DIM; ++k) o += gv[k] * C2[k * NUM_CLASSES + j];
        out[g * NUM_CLASSES + j] = o;
    }
}

extern "C" void kernel_launch(void* const* d_in, const int* in_sizes, int n_in,
                              void* d_out, int out_size, void* d_ws, size_t ws_size,
                              hipStream_t stream) {
    const float* x    = (const float*)d_in[0];
    const int*   ei   = (const int*)d_in[1];
    const int*   batch= (const int*)d_in[2];
    const float* W1   = (const float*)d_in[3];
    const float* b1   = (const float*)d_in[4];
    const float* W2   = (const float*)d_in[5];
    const float* b2   = (const float*)d_in[6];
    const float* W3   = (const float*)d_in[7];
    const float* b3   = (const float*)d_in[8];
    const float* C1   = (const float*)d_in[9];
    const float* bc1  = (const float*)d_in[10];
    const float* C2   = (const float*)d_in[11];
    const float* bc2  = (const float*)d_in[12];

    const int nedges = in_sizes[1] / 2;
    const int* src = ei;
    const int* dst = ei + nedges;

    // workspace layout (4-byte units)
    float*    dinv    = (float*)d_ws;                           // NPAD
    uint_t*   TbA     = (uint_t*)(dinv + NPAD);                 // N_NODES*64
    uint_t*   TbB     = TbA + (long long)N_NODES * 64;          // N_NODES*64
    float*    pooled  = (float*)(TbB + (long long)N_NODES * 64);// 8192
    float*    counts  = pooled + NUM_GRAPHS * DIM;              // 64
    int*      degi    = (int*)(counts + 64);                    // NPAD
    int*      rowptr  = degi + NPAD;                            // NPAD+256
    int*      bsum    = rowptr + NPAD + 256;                    // 256
    int*      rank    = bsum + 256;                             // nedges
    int*      csr_src = rank + nedges;                          // nedges
    ushort_t* Wt      = (ushort_t*)(csr_src + nedges);          // 3*16384 bf16

    const int nodeBlocks = NPAD / 256;                     // 196
    const int mmBlocks   = (N_NODES + 63) / 64;            // 782
    const int fusedBlocks= (N_NODES + 15) / 16;            // 3125
    const int pgBlocks   = (N_NODES + 31) / 32;            // 1563
    const int edgeBlocks = (nedges + 255) / 256;           // 3125

    k_init<<<nodeBlocks, 256, 0, stream>>>(degi, pooled, counts);
    k_prep<<<192, 256, 0, stream>>>(W1, W2, W3, Wt);
    k_count<<<edgeBlocks, 256, 0, stream>>>(dst, degi, rank, nedges);
    k_scan1<<<nodeBlocks, 256, 0, stream>>>(degi, rowptr, bsum);
    k_scan2<<<1, 256, 0, stream>>>(bsum, nodeBlocks);
    k_scan3<<<nodeBlocks, 256, 0, stream>>>(rowptr, bsum, degi, dinv);
    k_fill<<<edgeBlocks, 256, 0, stream>>>(src, dst, rank, rowptr, csr_src, nedges);

    k_mm1<<<mmBlocks, 256, 0, stream>>>(x, Wt, dinv, (ushort_t*)TbA);
    k_fused<<<fusedBlocks, 256, 0, stream>>>(rowptr, csr_src, dinv, TbA,
                                             Wt + 16384, b1, (ushort_t*)TbB);
    k_fused<<<fusedBlocks, 256, 0, stream>>>(rowptr, csr_src, dinv, TbB,
                                             Wt + 32768, b2, (ushort_t*)TbA);
    k_poolgather<<<pgBlocks, 256, 0, stream>>>(rowptr, csr_src, dinv, TbA,
                                               b3, batch, pooled, counts);
    k_cls<<<NUM_GRAPHS, 128, 0, stream>>>(pooled, counts, C1, bc1, C2, bc2,
                                          (float*)d_out);
}

// Round 3
// 332.138 us; speedup vs baseline: 1.0074x; 1.0074x over previous
//
#include <hip/hip_runtime.h>
#include <hip/hip_bf16.h>

#define N_NODES    50000
#define DIM        128
#define NUM_GRAPHS 64
#define NUM_CLASSES 3
#define NPAD       50176   // 196*256
#define XPITCH     136     // LDS row pitch in ushorts (17 x 16B, odd -> conflict-free b128)

typedef unsigned short ushort_t;
typedef unsigned int   uint_t;
typedef __attribute__((ext_vector_type(8))) short short8;
typedef __attribute__((ext_vector_type(4))) float f32x4;

__device__ __forceinline__ ushort_t f2bf(float f) {
    union { float f; uint_t u; } v; v.f = f;
    uint_t r = v.u + 0x7fffu + ((v.u >> 16) & 1u);   // RNE
    return (ushort_t)(r >> 16);
}
__device__ __forceinline__ float bflo(uint_t u) {
    union { uint_t u; float f; } v; v.u = u << 16; return v.f;
}
__device__ __forceinline__ float bfhi(uint_t u) {
    union { uint_t u; float f; } v; v.u = u & 0xffff0000u; return v.f;
}

// load 8 edge rows; indices come from the in-register idx vector via readlane
// (scalar path, no memory dependency) -> row loads issue back-to-back.
__device__ __forceinline__ void load8(uint_t* u, int myidx, int jbase,
                                      const uint_t* __restrict__ Tb, int lane) {
    #pragma unroll
    for (int q = 0; q < 8; ++q) {
        int s = __shfl(myidx, jbase + q);   // v_readlane -> uniform
        u[q] = Tb[s * 64 + lane];
    }
}

// Shuffle-indexed gather: caller provides the node's first 64 indices in
// myidx0 (one coalesced load, prefetchable). Row loads rotate 8-deep:
// batch b+1 issues before batch b is consumed; no idx loads on the path.
// acc += self row + sum of neighbor rows (lane holds channels 2*lane, 2*lane+1).
__device__ __forceinline__ void gather_sh(
    int n, int lane, int myidx0, int p0, int p1,
    const int* __restrict__ csr_src, const uint_t* __restrict__ Tb,
    float2& acc)
{
    uint_t us = Tb[n * 64 + lane];      // self loop (issues first)
    float2 a0 = make_float2(bflo(us), bfhi(us));
    float2 a1 = make_float2(0.f, 0.f);
    int deg = p1 - p0;
    if (deg < 0) deg = 0;
    int nchunk = (deg + 63) >> 6;       // bounded: provably terminates
    int myidx = myidx0;
    for (int ck = 0; ck < nchunk; ++ck) {
        int base = p0 + ck * 64;
        int cnt = p1 - base; if (cnt > 64) cnt = 64;
        int nb = cnt >> 3;
        if (nb > 0) {
            uint_t ucur[8];
            load8(ucur, myidx, 0, Tb, lane);
            for (int b = 1; b < nb; ++b) {
                uint_t unxt[8];
                load8(unxt, myidx, b * 8, Tb, lane);
                #pragma unroll
                for (int q = 0; q < 8; q += 2) {
                    a0.x += bflo(ucur[q]);     a0.y += bfhi(ucur[q]);
                    a1.x += bflo(ucur[q + 1]); a1.y += bfhi(ucur[q + 1]);
                }
                #pragma unroll
                for (int q = 0; q < 8; ++q) ucur[q] = unxt[q];
            }
            #pragma unroll
            for (int q = 0; q < 8; q += 2) {
                a0.x += bflo(ucur[q]);     a0.y += bfhi(ucur[q]);
                a1.x += bflo(ucur[q + 1]); a1.y += bfhi(ucur[q + 1]);
            }
        }
        for (int j = nb * 8; j < cnt; ++j) {
            int s = __shfl(myidx, j);
            uint_t u = Tb[s * 64 + lane];
            a0.x += bflo(u); a0.y += bfhi(u);
        }
        if (ck + 1 < nchunk) {          // rare: degree > 64
            int nb2 = p1 - (base + 64);
            myidx = (lane < nb2) ? csr_src[base + 64 + lane] : 0;
        }
    }
    acc.x += a0.x + a1.x;
    acc.y += a0.y + a1.y;
}

// ---------------- init ----------------
__global__ void k_init(int* degi, float* pooled, float* counts) {
    int i = blockIdx.x * 256 + threadIdx.x;
    if (i < NPAD) degi[i] = 0;
    if (i < NUM_GRAPHS * DIM) pooled[i] = 0.0f;
    if (i < NUM_GRAPHS) counts[i] = 0.0f;
}

// ---------------- W -> Wt bf16 transpose (all 3 layers) ----------------
__global__ void k_prep(const float* __restrict__ W1, const float* __restrict__ W2,
                       const float* __restrict__ W3, ushort_t* __restrict__ Wt) {
    int i = blockIdx.x * 256 + threadIdx.x;
    int mat = i >> 14;
    int idx = i & 16383;
    const float* W = (mat == 0) ? W1 : (mat == 1) ? W2 : W3;
    int n = idx >> 7, k = idx & 127;
    Wt[mat * 16384 + n * 128 + k] = f2bf(W[k * 128 + n]);
}

// ---------------- degree histogram; atomic return = within-row rank ----------------
__global__ void k_count(const int* __restrict__ dst, int* degi, int* rank, int nedges) {
    int e = blockIdx.x * 256 + threadIdx.x;
    if (e < nedges) rank[e] = atomicAdd(&degi[dst[e]], 1);
}

// ---------------- scan ----------------
__global__ __launch_bounds__(256) void k_scan1(const int* __restrict__ degi,
                                               int* rowptr, int* bsum) {
    __shared__ int sh[256];
    int i = blockIdx.x * 256 + threadIdx.x;
    int v = degi[i];
    sh[threadIdx.x] = v;
    __syncthreads();
    for (int off = 1; off < 256; off <<= 1) {
        int t = (threadIdx.x >= off) ? sh[threadIdx.x - off] : 0;
        __syncthreads();
        sh[threadIdx.x] += t;
        __syncthreads();
    }
    rowptr[i] = sh[threadIdx.x] - v;
    if (threadIdx.x == 255) bsum[blockIdx.x] = sh[255];
}

__global__ __launch_bounds__(256) void k_scan2(int* bsum, int nblocks) {
    __shared__ int sh[256];
    int v = (threadIdx.x < nblocks) ? bsum[threadIdx.x] : 0;
    sh[threadIdx.x] = v;
    __syncthreads();
    for (int off = 1; off < 256; off <<= 1) {
        int t = (threadIdx.x >= off) ? sh[threadIdx.x - off] : 0;
        __syncthreads();
        sh[threadIdx.x] += t;
        __syncthreads();
    }
    if (threadIdx.x < nblocks) bsum[threadIdx.x] = sh[threadIdx.x] - v;
}

__global__ __launch_bounds__(256) void k_scan3(int* rowptr, const int* __restrict__ bsum,
                                               const int* __restrict__ degi,
                                               float* dinv) {
    int i = blockIdx.x * 256 + threadIdx.x;
    rowptr[i] = rowptr[i] + bsum[blockIdx.x];
    if (i < N_NODES) dinv[i] = rsqrtf((float)degi[i] + 1.0f);
}

// ---------------- CSR fill: atomic-free scatter via precomputed rank ----------------
__global__ void k_fill(const int* __restrict__ src, const int* __restrict__ dst,
                       const int* __restrict__ rank, const int* __restrict__ rowptr,
                       int* csr_src, int nedges) {
    int e = blockIdx.x * 256 + threadIdx.x;
    if (e < nedges) csr_src[rowptr[dst[e]] + rank[e]] = src[e];
}

// ---------------- layer-1 matmul: Tb1' = (x @ W1) * dinv[row] ----------------
__global__ __launch_bounds__(256) void k_mm1(
    const float* __restrict__ xin, const ushort_t* __restrict__ WtG,
    const float* __restrict__ dinv, ushort_t* __restrict__ TbOut)
{
    __shared__ ushort_t Wl[DIM * XPITCH];
    __shared__ ushort_t Xl[64 * XPITCH];

    const int tid = threadIdx.x;
    const int rowbase = blockIdx.x * 64;

    #pragma unroll
    for (int i = 0; i < 8; ++i) {
        int g = tid + i * 256;
        uint4 v = ((const uint4*)WtG)[g];
        *((uint4*)&Wl[(g >> 4) * XPITCH + (g & 15) * 8]) = v;
    }
    #pragma unroll
    for (int i = 0; i < 8; ++i) {
        int c = tid + i * 256;
        int row = c >> 5;
        int grow = rowbase + row;
        float4 f = make_float4(0.f, 0.f, 0.f, 0.f);
        if (grow < N_NODES)
            f = ((const float4*)xin)[(long long)rowbase * 32 + c];
        ushort4 h;
        h.x = f2bf(f.x); h.y = f2bf(f.y); h.z = f2bf(f.z); h.w = f2bf(f.w);
        *((ushort4*)&Xl[row * XPITCH + (c & 31) * 4]) = h;
    }
    __syncthreads();

    const int wave = tid >> 6;
    const int lane = tid & 63;
    const int quad = lane >> 4;
    const int lm   = lane & 15;
    const int m0   = wave * 16;

    short8 af[4];
    #pragma unroll
    for (int k0 = 0; k0 < 4; ++k0)
        af[k0] = *(const short8*)&Xl[(m0 + lm) * XPITCH + k0 * 32 + quad * 8];

    int noder[4]; float di[4]; bool okr[4];
    #pragma unroll
    for (int r = 0; r < 4; ++r) {
        noder[r] = rowbase + m0 + quad * 4 + r;
        okr[r] = (noder[r] < N_NODES);
        di[r] = okr[r] ? dinv[noder[r]] : 0.f;
    }

    for (int n0 = 0; n0 < DIM; n0 += 16) {
        f32x4 acc = {0.f, 0.f, 0.f, 0.f};
        #pragma unroll
        for (int k0 = 0; k0 < 4; ++k0) {
            short8 bf = *(const short8*)&Wl[(n0 + lm) * XPITCH + k0 * 32 + quad * 8];
            acc = __builtin_amdgcn_mfma_f32_16x16x32_bf16(af[k0], bf, acc, 0, 0, 0);
        }
        int n = n0 + lm;
        #pragma unroll
        for (int r = 0; r < 4; ++r)
            if (okr[r])
                TbOut[(long long)noder[r] * DIM + n] = f2bf(acc[r] * di[r]);
    }
}

// ---------------- fused: X = ReLU(b + dinv[n]*Sum Tb'[s]) ; Tb_out' = (X@W)*dinv ----------------
__global__ __launch_bounds__(256) void k_fused(
    const int* __restrict__ rowptr, const int* __restrict__ csr_src,
    const float* __restrict__ dinv, const uint_t* __restrict__ TbIn,
    const ushort_t* __restrict__ WtG, const float* __restrict__ b_prev,
    ushort_t* __restrict__ TbOut)
{
    __shared__ ushort_t Xl[16 * XPITCH];   // 4352 B

    const int tid = threadIdx.x;
    const int rowbase = blockIdx.x * 16;
    const int wave = tid >> 6;
    const int lane = tid & 63;

    float2 bias2 = ((const float2*)b_prev)[lane];

    // rowptr for this wave's 4 nodes: one coalesced load + readlane
    const int nfirst = rowbase + wave * 4;
    int pv = (lane < 5) ? rowptr[nfirst + lane] : 0;
    int p[5];
    #pragma unroll
    for (int i = 0; i < 5; ++i) p[i] = __shfl(pv, i);

    // prefetch node 0's index vector
    int idx_n;
    {
        int d0 = p[1] - p[0];
        idx_n = (lane < d0) ? csr_src[p[0] + lane] : 0;
    }

    #pragma unroll
    for (int t = 0; t < 4; ++t) {
        int idx_cur = idx_n;
        if (t < 3) {                        // prefetch next node's indices
            int dn = p[t + 2] - p[t + 1];
            idx_n = (lane < dn) ? csr_src[p[t + 1] + lane] : 0;
        }
        int r = wave * 4 + t;
        int n = rowbase + r;
        float2 acc = make_float2(0.f, 0.f);
        float dd = 0.f;
        if (n < N_NODES) {
            dd = dinv[n];
            gather_sh(n, lane, idx_cur, p[t], p[t + 1], csr_src, TbIn, acc);
        }
        ushort2 h;
        h.x = f2bf(fmaxf(bias2.x + acc.x * dd, 0.f));
        h.y = f2bf(fmaxf(bias2.y + acc.y * dd, 0.f));
        *((ushort2*)&Xl[r * XPITCH + lane * 2]) = h;
    }
    __syncthreads();

    const int quad = lane >> 4;
    const int lm   = lane & 15;

    short8 af[4];
    #pragma unroll
    for (int k0 = 0; k0 < 4; ++k0)
        af[k0] = *(const short8*)&Xl[lm * XPITCH + k0 * 32 + quad * 8];

    int noder[4]; float di[4]; bool okr[4];
    #pragma unroll
    for (int r = 0; r < 4; ++r) {
        noder[r] = rowbase + quad * 4 + r;
        okr[r] = (noder[r] < N_NODES);
        di[r] = okr[r] ? dinv[noder[r]] : 0.f;
    }

    #pragma unroll
    for (int h = 0; h < 2; ++h) {
        int n0 = wave * 32 + h * 16;
        f32x4 acc = {0.f, 0.f, 0.f, 0.f};
        #pragma unroll
        for (int k0 = 0; k0 < 4; ++k0) {
            short8 bf = *(const short8*)&WtG[(n0 + lm) * DIM + k0 * 32 + quad * 8];
            acc = __builtin_amdgcn_mfma_f32_16x16x32_bf16(af[k0], bf, acc, 0, 0, 0);
        }
        int n = n0 + lm;
        #pragma unroll
        for (int r = 0; r < 4; ++r)
            if (okr[r])
                TbOut[(long long)noder[r] * DIM + n] = f2bf(acc[r] * di[r]);
    }
}

// ---------------- fused gather + mean-pool, LDS flush accumulation ----------------
// 8-row strips; shuffle-indexed gather with rowptr/idx prefetch across nodes.
__global__ __launch_bounds__(256) void k_poolgather(
    const int* __restrict__ rowptr, const int* __restrict__ csr_src,
    const float* __restrict__ dinv, const uint_t* __restrict__ Tb,
    const float* __restrict__ b3, const int* __restrict__ batch,
    float* pooled, float* counts)
{
    __shared__ float lp[8][DIM];   // 4 KB
    __shared__ float lc[8];

    const int tid  = threadIdx.x;
    const int wave = tid >> 6;
    const int lane = tid & 63;
    const int blk0 = blockIdx.x * 32;

    #pragma unroll
    for (int i = 0; i < 4; ++i) ((float*)lp)[tid + i * 256] = 0.f;
    if (tid < 8) lc[tid] = 0.f;
    __syncthreads();

    const int gbase = batch[min(blk0, N_NODES - 1)];
    int n0 = blk0 + wave * 8;

    if (n0 < N_NODES) {
        int nend = min(n0 + 8, N_NODES);
        float2 bias2 = ((const float2*)b3)[lane];

        // rowptr for this wave's strip: one coalesced load + readlane
        int pv = (lane < 9) ? rowptr[min(n0 + lane, NPAD)] : 0;
        int p[9];
        #pragma unroll
        for (int i = 0; i < 9; ++i) p[i] = __shfl(pv, i);

        int cur = batch[n0];
        int runstart = n0;
        float2 pacc = make_float2(0.f, 0.f);

        int idx_n;
        {
            int d0 = p[1] - p[0];
            idx_n = (lane < d0) ? csr_src[p[0] + lane] : 0;
        }

        for (int i = 0; i < nend - n0; ++i) {
            int n = n0 + i;
            int idx_cur = idx_n;
            if (i < 7) {
                int dn = p[i + 2] - p[i + 1];
                idx_n = (lane < dn) ? csr_src[p[i + 1] + lane] : 0;
            }
            int g = batch[n];
            if (g != cur) {
                int slot = cur - gbase;
                if (slot < 8) {
                    atomicAdd(&lp[slot][2 * lane], pacc.x);
                    atomicAdd(&lp[slot][2 * lane + 1], pacc.y);
                    if (lane == 0) atomicAdd(&lc[slot], (float)(n - runstart));
                } else {
                    atomicAdd(&pooled[cur * DIM + 2 * lane], pacc.x);
                    atomicAdd(&pooled[cur * DIM + 2 * lane + 1], pacc.y);
                    if (lane == 0) atomicAdd(&counts[cur], (float)(n - runstart));
                }
                pacc.x = 0.f; pacc.y = 0.f; cur = g; runstart = n;
            }
            float2 acc = make_float2(0.f, 0.f);
            gather_sh(n, lane, idx_cur, p[i], p[i + 1], csr_src, Tb, acc);
            float dd = dinv[n];
            pacc.x += bias2.x + acc.x * dd;
            pacc.y += bias2.y + acc.y * dd;
        }
        int slot = cur - gbase;
        if (slot < 8) {
            atomicAdd(&lp[slot][2 * lane], pacc.x);
            atomicAdd(&lp[slot][2 * lane + 1], pacc.y);
            if (lane == 0) atomicAdd(&lc[slot], (float)(nend - runstart));
        } else {
            atomicAdd(&pooled[cur * DIM + 2 * lane], pacc.x);
            atomicAdd(&pooled[cur * DIM + 2 * lane + 1], pacc.y);
            if (lane == 0) atomicAdd(&counts[cur], (float)(nend - runstart));
        }
    }
    __syncthreads();

    #pragma unroll
    for (int s = 0; s < 8; ++s) {
        if (lc[s] != 0.f) {
            if (tid < DIM) atomicAdd(&pooled[(gbase + s) * DIM + tid], lp[s][tid]);
            if (tid == DIM) atomicAdd(&counts[gbase + s], lc[s]);
        }
    }
}

// ---------------- classifier head ----------------
__global__ __launch_bounds__(128) void k_cls(
    const float* __restrict__ pooled, const float* __restrict__ counts,
    const float* __restrict__ C1, const float* __restrict__ bc1,
    const float* __restrict__ C2, const float* __restrict__ bc2,
    float* out)
{
    __shared__ float pm[DIM];
    __shared__ float gv[DIM];
    int g = blockIdx.x, j = threadIdx.x;
    float cnt = fmaxf(counts[g], 1.0f);
    pm[j] = pooled[g * DIM + j] / cnt;
    __syncthreads();
    float a = bc1[j];
    for (int k = 0; k < DIM; ++k) a += pm[k] * C1[k * DIM + j];
    gv[j] = fmaxf(a, 0.f);
    __syncthreads();
    if (j < NUM_CLASSES) {
        float o = bc2[j];
        for (int k = 0; k < DIM; ++k) o += gv[k] * C2[k * NUM_CLASSES + j];
        out[g * NUM_CLASSES + j] = o;
    }
}

extern "C" void kernel_launch(void* const* d_in, const int* in_sizes, int n_in,
                              void* d_out, int out_size, void* d_ws, size_t ws_size,
                              hipStream_t stream) {
    const float* x    = (const float*)d_in[0];
    const int*   ei   = (const int*)d_in[1];
    const int*   batch= (const int*)d_in[2];
    const float* W1   = (const float*)d_in[3];
    const float* b1   = (const float*)d_in[4];
    const float* W2   = (const float*)d_in[5];
    const float* b2   = (const float*)d_in[6];
    const float* W3   = (const float*)d_in[7];
    const float* b3   = (const float*)d_in[8];
    const float* C1   = (const float*)d_in[9];
    const float* bc1  = (const float*)d_in[10];
    const float* C2   = (const float*)d_in[11];
    const float* bc2  = (const float*)d_in[12];

    const int nedges = in_sizes[1] / 2;
    const int* src = ei;
    const int* dst = ei + nedges;

    // workspace layout (4-byte units)
    float*    dinv    = (float*)d_ws;                           // NPAD
    uint_t*   TbA     = (uint_t*)(dinv + NPAD);                 // N_NODES*64
    uint_t*   TbB     = TbA + (long long)N_NODES * 64;          // N_NODES*64
    float*    pooled  = (float*)(TbB + (long long)N_NODES * 64);// 8192
    float*    counts  = pooled + NUM_GRAPHS * DIM;              // 64
    int*      degi    = (int*)(counts + 64);                    // NPAD
    int*      rowptr  = degi + NPAD;                            // NPAD+256
    int*      bsum    = rowptr + NPAD + 256;                    // 256
    int*      rank    = bsum + 256;                             // nedges
    int*      csr_src = rank + nedges;                          // nedges
    ushort_t* Wt      = (ushort_t*)(csr_src + nedges);          // 3*16384 bf16

    const int nodeBlocks = NPAD / 256;                     // 196
    const int mmBlocks   = (N_NODES + 63) / 64;            // 782
    const int fusedBlocks= (N_NODES + 15) / 16;            // 3125
    const int pgBlocks   = (N_NODES + 31) / 32;            // 1563
    const int edgeBlocks = (nedges + 255) / 256;           // 3125

    k_init<<<nodeBlocks, 256, 0, stream>>>(degi, pooled, counts);
    k_prep<<<192, 256, 0, stream>>>(W1, W2, W3, Wt);
    k_count<<<edgeBlocks, 256, 0, stream>>>(dst, degi, rank, nedges);
    k_scan1<<<nodeBlocks, 256, 0, stream>>>(degi, rowptr, bsum);
    k_scan2<<<1, 256, 0, stream>>>(bsum, nodeBlocks);
    k_scan3<<<nodeBlocks, 256, 0, stream>>>(rowptr, bsum, degi, dinv);
    k_fill<<<edgeBlocks, 256, 0, stream>>>(src, dst, rank, rowptr, csr_src, nedges);

    k_mm1<<<mmBlocks, 256, 0, stream>>>(x, Wt, dinv, (ushort_t*)TbA);
    k_fused<<<fusedBlocks, 256, 0, stream>>>(rowptr, csr_src, dinv, TbA,
                                             Wt + 16384, b1, (ushort_t*)TbB);
    k_fused<<<fusedBlocks, 256, 0, stream>>>(rowptr, csr_src, dinv, TbB,
                                             Wt + 32768, b2, (ushort_t*)TbA);
    k_poolgather<<<pgBlocks, 256, 0, stream>>>(rowptr, csr_src, dinv, TbA,
                                               b3, batch, pooled, counts);
    k_cls<<<NUM_GRAPHS, 128, 0, stream>>>(pooled, counts, C1, bc1, C2, bc2,
                                          (float*)d_out);
}

// Round 4
// 322.985 us; speedup vs baseline: 1.0360x; 1.0283x over previous
//
#include <hip/hip_runtime.h>
#include <hip/hip_bf16.h>

#define N_NODES    50000
#define DIM        128
#define NUM_GRAPHS 64
#define NUM_CLASSES 3
#define NPAD       50176   // 196*256
#define XPITCH     136     // LDS row pitch in ushorts (17 x 16B, odd -> conflict-free b128)

typedef unsigned short ushort_t;
typedef unsigned int   uint_t;
typedef __attribute__((ext_vector_type(8))) short short8;
typedef __attribute__((ext_vector_type(4))) float f32x4;

__device__ __forceinline__ ushort_t f2bf(float f) {
    union { float f; uint_t u; } v; v.f = f;
    uint_t r = v.u + 0x7fffu + ((v.u >> 16) & 1u);   // RNE
    return (ushort_t)(r >> 16);
}
__device__ __forceinline__ float bflo(uint_t u) {
    union { uint_t u; float f; } v; v.u = u << 16; return v.f;
}
__device__ __forceinline__ float bfhi(uint_t u) {
    union { uint_t u; float f; } v; v.u = u & 0xffff0000u; return v.f;
}

// raw gather, software-pipelined: acc += sum over {n} u N(n) of Tb'[s]
// (Tb' rows pre-scaled by dinv[s]; caller multiplies by dinv[n].)
// Double-buffered 8-batches: batch b+1's loads issue before batch b is consumed,
// so the accumulate waits on vmcnt(8) while 8 newer loads stay in flight.
// PROVEN core (round-0, 303 us) -- do not restructure (rounds 1/3 regressed).
__device__ __forceinline__ void gather_raw(
    int n, int lane, const int* __restrict__ rowptr,
    const int* __restrict__ csr_src, const uint_t* __restrict__ Tb,
    float2& acc)
{
    int p0 = rowptr[n], p1 = rowptr[n + 1];
    uint_t us = Tb[n * 64 + lane];      // self loop
    float2 a0 = make_float2(bflo(us), bfhi(us));
    float2 a1 = make_float2(0.f, 0.f);
    int p = p0;
    int nb = (p1 - p0) >> 3;            // full 8-batches
    if (nb > 0) {
        uint_t ucur[8];
        #pragma unroll
        for (int q = 0; q < 8; ++q) ucur[q] = Tb[csr_src[p + q] * 64 + lane];
        for (int b = 1; b < nb; ++b) {
            uint_t unxt[8];
            #pragma unroll
            for (int q = 0; q < 8; ++q) unxt[q] = Tb[csr_src[p + 8 + q] * 64 + lane];
            #pragma unroll
            for (int q = 0; q < 8; q += 2) {
                a0.x += bflo(ucur[q]);     a0.y += bfhi(ucur[q]);
                a1.x += bflo(ucur[q + 1]); a1.y += bfhi(ucur[q + 1]);
            }
            #pragma unroll
            for (int q = 0; q < 8; ++q) ucur[q] = unxt[q];
            p += 8;
        }
        #pragma unroll
        for (int q = 0; q < 8; q += 2) {
            a0.x += bflo(ucur[q]);     a0.y += bfhi(ucur[q]);
            a1.x += bflo(ucur[q + 1]); a1.y += bfhi(ucur[q + 1]);
        }
        p += 8;
    }
    for (; p + 4 <= p1; p += 4) {
        int s[4]; uint_t u[4];
        #pragma unroll
        for (int q = 0; q < 4; ++q) s[q] = csr_src[p + q];
        #pragma unroll
        for (int q = 0; q < 4; ++q) u[q] = Tb[s[q] * 64 + lane];
        #pragma unroll
        for (int q = 0; q < 4; q += 2) {
            a0.x += bflo(u[q]);     a0.y += bfhi(u[q]);
            a1.x += bflo(u[q + 1]); a1.y += bfhi(u[q + 1]);
        }
    }
    for (; p < p1; ++p) {
        int s = csr_src[p];
        uint_t u = Tb[s * 64 + lane];
        a0.x += bflo(u); a0.y += bfhi(u);
    }
    acc.x += a0.x + a1.x;
    acc.y += a0.y + a1.y;
}

// ---------------- init ----------------
__global__ void k_init(int* degi, float* pooled, float* counts) {
    int i = blockIdx.x * 256 + threadIdx.x;
    if (i < NPAD) degi[i] = 0;
    if (i < NUM_GRAPHS * DIM) pooled[i] = 0.0f;
    if (i < NUM_GRAPHS) counts[i] = 0.0f;
}

// ---------------- W -> Wt bf16 transpose (all 3 layers) ----------------
__global__ void k_prep(const float* __restrict__ W1, const float* __restrict__ W2,
                       const float* __restrict__ W3, ushort_t* __restrict__ Wt) {
    int i = blockIdx.x * 256 + threadIdx.x;
    int mat = i >> 14;
    int idx = i & 16383;
    const float* W = (mat == 0) ? W1 : (mat == 1) ? W2 : W3;
    int n = idx >> 7, k = idx & 127;
    Wt[mat * 16384 + n * 128 + k] = f2bf(W[k * 128 + n]);
}

// ---------------- degree histogram; atomic return = within-row rank ----------------
__global__ void k_count(const int* __restrict__ dst, int* degi, int* rank, int nedges) {
    int e = blockIdx.x * 256 + threadIdx.x;
    if (e < nedges) rank[e] = atomicAdd(&degi[dst[e]], 1);
}

// ---------------- scan ----------------
__global__ __launch_bounds__(256) void k_scan1(const int* __restrict__ degi,
                                               int* rowptr, int* bsum) {
    __shared__ int sh[256];
    int i = blockIdx.x * 256 + threadIdx.x;
    int v = degi[i];
    sh[threadIdx.x] = v;
    __syncthreads();
    for (int off = 1; off < 256; off <<= 1) {
        int t = (threadIdx.x >= off) ? sh[threadIdx.x - off] : 0;
        __syncthreads();
        sh[threadIdx.x] += t;
        __syncthreads();
    }
    rowptr[i] = sh[threadIdx.x] - v;
    if (threadIdx.x == 255) bsum[blockIdx.x] = sh[255];
}

__global__ __launch_bounds__(256) void k_scan2(int* bsum, int nblocks) {
    __shared__ int sh[256];
    int v = (threadIdx.x < nblocks) ? bsum[threadIdx.x] : 0;
    sh[threadIdx.x] = v;
    __syncthreads();
    for (int off = 1; off < 256; off <<= 1) {
        int t = (threadIdx.x >= off) ? sh[threadIdx.x - off] : 0;
        __syncthreads();
        sh[threadIdx.x] += t;
        __syncthreads();
    }
    if (threadIdx.x < nblocks) bsum[threadIdx.x] = sh[threadIdx.x] - v;
}

__global__ __launch_bounds__(256) void k_scan3(int* rowptr, const int* __restrict__ bsum,
                                               const int* __restrict__ degi,
                                               float* dinv) {
    int i = blockIdx.x * 256 + threadIdx.x;
    rowptr[i] = rowptr[i] + bsum[blockIdx.x];
    if (i < N_NODES) dinv[i] = rsqrtf((float)degi[i] + 1.0f);
}

// ---------------- CSR fill: atomic-free scatter via precomputed rank ----------------
__global__ void k_fill(const int* __restrict__ src, const int* __restrict__ dst,
                       const int* __restrict__ rank, const int* __restrict__ rowptr,
                       int* csr_src, int nedges) {
    int e = blockIdx.x * 256 + threadIdx.x;
    if (e < nedges) csr_src[rowptr[dst[e]] + rank[e]] = src[e];
}

// ---------------- layer-1 matmul: Tb1' = (x @ W1) * dinv[row] ----------------
__global__ __launch_bounds__(256) void k_mm1(
    const float* __restrict__ xin, const ushort_t* __restrict__ WtG,
    const float* __restrict__ dinv, ushort_t* __restrict__ TbOut)
{
    __shared__ ushort_t Wl[DIM * XPITCH];
    __shared__ ushort_t Xl[64 * XPITCH];

    const int tid = threadIdx.x;
    const int rowbase = blockIdx.x * 64;

    #pragma unroll
    for (int i = 0; i < 8; ++i) {
        int g = tid + i * 256;
        uint4 v = ((const uint4*)WtG)[g];
        *((uint4*)&Wl[(g >> 4) * XPITCH + (g & 15) * 8]) = v;
    }
    #pragma unroll
    for (int i = 0; i < 8; ++i) {
        int c = tid + i * 256;
        int row = c >> 5;
        int grow = rowbase + row;
        float4 f = make_float4(0.f, 0.f, 0.f, 0.f);
        if (grow < N_NODES)
            f = ((const float4*)xin)[(long long)rowbase * 32 + c];
        ushort4 h;
        h.x = f2bf(f.x); h.y = f2bf(f.y); h.z = f2bf(f.z); h.w = f2bf(f.w);
        *((ushort4*)&Xl[row * XPITCH + (c & 31) * 4]) = h;
    }
    __syncthreads();

    const int wave = tid >> 6;
    const int lane = tid & 63;
    const int quad = lane >> 4;
    const int lm   = lane & 15;
    const int m0   = wave * 16;

    short8 af[4];
    #pragma unroll
    for (int k0 = 0; k0 < 4; ++k0)
        af[k0] = *(const short8*)&Xl[(m0 + lm) * XPITCH + k0 * 32 + quad * 8];

    int noder[4]; float di[4]; bool okr[4];
    #pragma unroll
    for (int r = 0; r < 4; ++r) {
        noder[r] = rowbase + m0 + quad * 4 + r;
        okr[r] = (noder[r] < N_NODES);
        di[r] = okr[r] ? dinv[noder[r]] : 0.f;
    }

    for (int n0 = 0; n0 < DIM; n0 += 16) {
        f32x4 acc = {0.f, 0.f, 0.f, 0.f};
        #pragma unroll
        for (int k0 = 0; k0 < 4; ++k0) {
            short8 bf = *(const short8*)&Wl[(n0 + lm) * XPITCH + k0 * 32 + quad * 8];
            acc = __builtin_amdgcn_mfma_f32_16x16x32_bf16(af[k0], bf, acc, 0, 0, 0);
        }
        int n = n0 + lm;
        #pragma unroll
        for (int r = 0; r < 4; ++r)
            if (okr[r])
                TbOut[(long long)noder[r] * DIM + n] = f2bf(acc[r] * di[r]);
    }
}

// ---------------- fused: X = ReLU(b + dinv[n]*Sum Tb'[s]) ; Tb_out' = (X@W)*dinv ----------------
// TLP version: 1024 threads = 16 waves, ONE node per wave (round-0 had 4 nodes/wave
// serial; occupancy 50-59% and nothing saturated -> latency-bound on wave count).
// Same 3125-block grid, 4x resident gather waves. MFMA phase: waves 0-7 take one
// 16-col tile each (16 rows x 128 cols total, unchanged math).
__global__ __launch_bounds__(1024) void k_fused(
    const int* __restrict__ rowptr, const int* __restrict__ csr_src,
    const float* __restrict__ dinv, const uint_t* __restrict__ TbIn,
    const ushort_t* __restrict__ WtG, const float* __restrict__ b_prev,
    ushort_t* __restrict__ TbOut)
{
    __shared__ ushort_t Xl[16 * XPITCH];   // 4352 B

    const int tid = threadIdx.x;
    const int rowbase = blockIdx.x * 16;
    const int wave = tid >> 6;             // 0..15
    const int lane = tid & 63;

    float2 bias2 = ((const float2*)b_prev)[lane];

    {
        int r = wave;                      // one node per wave
        int n = rowbase + r;
        float2 acc = make_float2(0.f, 0.f);
        float dd = 0.f;
        if (n < N_NODES) {
            dd = dinv[n];
            gather_raw(n, lane, rowptr, csr_src, TbIn, acc);
        }
        ushort2 h;
        h.x = f2bf(fmaxf(bias2.x + acc.x * dd, 0.f));
        h.y = f2bf(fmaxf(bias2.y + acc.y * dd, 0.f));
        *((ushort2*)&Xl[r * XPITCH + lane * 2]) = h;
    }
    __syncthreads();

    if (wave < 8) {
        const int quad = lane >> 4;
        const int lm   = lane & 15;

        short8 af[4];
        #pragma unroll
        for (int k0 = 0; k0 < 4; ++k0)
            af[k0] = *(const short8*)&Xl[lm * XPITCH + k0 * 32 + quad * 8];

        int noder[4]; float di[4]; bool okr[4];
        #pragma unroll
        for (int r = 0; r < 4; ++r) {
            noder[r] = rowbase + quad * 4 + r;
            okr[r] = (noder[r] < N_NODES);
            di[r] = okr[r] ? dinv[noder[r]] : 0.f;
        }

        const int n0 = wave * 16;          // col tile
        f32x4 acc = {0.f, 0.f, 0.f, 0.f};
        #pragma unroll
        for (int k0 = 0; k0 < 4; ++k0) {
            short8 bf = *(const short8*)&WtG[(n0 + lm) * DIM + k0 * 32 + quad * 8];
            acc = __builtin_amdgcn_mfma_f32_16x16x32_bf16(af[k0], bf, acc, 0, 0, 0);
        }
        int n = n0 + lm;
        #pragma unroll
        for (int r = 0; r < 4; ++r)
            if (okr[r])
                TbOut[(long long)noder[r] * DIM + n] = f2bf(acc[r] * di[r]);
    }
}

// ---------------- fused gather + mean-pool, LDS flush accumulation ----------------
// 4-row strips (was 8): doubles grid to 3125 blocks for TLP/balance. Run flushes
// go to LDS slots (graph - gbase < 8); one global flush per block-graph at end.
__global__ __launch_bounds__(256) void k_poolgather(
    const int* __restrict__ rowptr, const int* __restrict__ csr_src,
    const float* __restrict__ dinv, const uint_t* __restrict__ Tb,
    const float* __restrict__ b3, const int* __restrict__ batch,
    float* pooled, float* counts)
{
    __shared__ float lp[8][DIM];   // 4 KB
    __shared__ float lc[8];

    const int tid  = threadIdx.x;
    const int wave = tid >> 6;
    const int lane = tid & 63;
    const int blk0 = blockIdx.x * 16;

    #pragma unroll
    for (int i = 0; i < 4; ++i) ((float*)lp)[tid + i * 256] = 0.f;
    if (tid < 8) lc[tid] = 0.f;
    __syncthreads();

    const int gbase = batch[min(blk0, N_NODES - 1)];
    int n0 = blk0 + wave * 4;

    if (n0 < N_NODES) {
        int nend = min(n0 + 4, N_NODES);
        float2 bias2 = ((const float2*)b3)[lane];
        int cur = batch[n0];
        int runstart = n0;
        float2 pacc = make_float2(0.f, 0.f);

        for (int n = n0; n < nend; ++n) {
            int g = batch[n];
            if (g != cur) {
                int slot = cur - gbase;
                if (slot < 8) {
                    atomicAdd(&lp[slot][2 * lane], pacc.x);
                    atomicAdd(&lp[slot][2 * lane + 1], pacc.y);
                    if (lane == 0) atomicAdd(&lc[slot], (float)(n - runstart));
                } else {
                    atomicAdd(&pooled[cur * DIM + 2 * lane], pacc.x);
                    atomicAdd(&pooled[cur * DIM + 2 * lane + 1], pacc.y);
                    if (lane == 0) atomicAdd(&counts[cur], (float)(n - runstart));
                }
                pacc.x = 0.f; pacc.y = 0.f; cur = g; runstart = n;
            }
            float2 acc = make_float2(0.f, 0.f);
            gather_raw(n, lane, rowptr, csr_src, Tb, acc);
            float dd = dinv[n];
            pacc.x += bias2.x + acc.x * dd;
            pacc.y += bias2.y + acc.y * dd;
        }
        int slot = cur - gbase;
        if (slot < 8) {
            atomicAdd(&lp[slot][2 * lane], pacc.x);
            atomicAdd(&lp[slot][2 * lane + 1], pacc.y);
            if (lane == 0) atomicAdd(&lc[slot], (float)(nend - runstart));
        } else {
            atomicAdd(&pooled[cur * DIM + 2 * lane], pacc.x);
            atomicAdd(&pooled[cur * DIM + 2 * lane + 1], pacc.y);
            if (lane == 0) atomicAdd(&counts[cur], (float)(nend - runstart));
        }
    }
    __syncthreads();

    #pragma unroll
    for (int s = 0; s < 8; ++s) {
        if (lc[s] != 0.f) {
            if (tid < DIM) atomicAdd(&pooled[(gbase + s) * DIM + tid], lp[s][tid]);
            if (tid == DIM) atomicAdd(&counts[gbase + s], lc[s]);
        }
    }
}

// ---------------- classifier head ----------------
__global__ __launch_bounds__(128) void k_cls(
    const float* __restrict__ pooled, const float* __restrict__ counts,
    const float* __restrict__ C1, const float* __restrict__ bc1,
    const float* __restrict__ C2, const float* __restrict__ bc2,
    float* out)
{
    __shared__ float pm[DIM];
    __shared__ float gv[DIM];
    int g = blockIdx.x, j = threadIdx.x;
    float cnt = fmaxf(counts[g], 1.0f);
    pm[j] = pooled[g * DIM + j] / cnt;
    __syncthreads();
    float a = bc1[j];
    for (int k = 0; k < DIM; ++k) a += pm[k] * C1[k * DIM + j];
    gv[j] = fmaxf(a, 0.f);
    __syncthreads();
    if (j < NUM_CLASSES) {
        float o = bc2[j];
        for (int k = 0; k < DIM; ++k) o += gv[k] * C2[k * NUM_CLASSES + j];
        out[g * NUM_CLASSES + j] = o;
    }
}

extern "C" void kernel_launch(void* const* d_in, const int* in_sizes, int n_in,
                              void* d_out, int out_size, void* d_ws, size_t ws_size,
                              hipStream_t stream) {
    const float* x    = (const float*)d_in[0];
    const int*   ei   = (const int*)d_in[1];
    const int*   batch= (const int*)d_in[2];
    const float* W1   = (const float*)d_in[3];
    const float* b1   = (const float*)d_in[4];
    const float* W2   = (const float*)d_in[5];
    const float* b2   = (const float*)d_in[6];
    const float* W3   = (const float*)d_in[7];
    const float* b3   = (const float*)d_in[8];
    const float* C1   = (const float*)d_in[9];
    const float* bc1  = (const float*)d_in[10];
    const float* C2   = (const float*)d_in[11];
    const float* bc2  = (const float*)d_in[12];

    const int nedges = in_sizes[1] / 2;
    const int* src = ei;
    const int* dst = ei + nedges;

    // workspace layout (4-byte units)
    float*    dinv    = (float*)d_ws;                           // NPAD
    uint_t*   TbA     = (uint_t*)(dinv + NPAD);                 // N_NODES*64
    uint_t*   TbB     = TbA + (long long)N_NODES * 64;          // N_NODES*64
    float*    pooled  = (float*)(TbB + (long long)N_NODES * 64);// 8192
    float*    counts  = pooled + NUM_GRAPHS * DIM;              // 64
    int*      degi    = (int*)(counts + 64);                    // NPAD
    int*      rowptr  = degi + NPAD;                            // NPAD+256
    int*      bsum    = rowptr + NPAD + 256;                    // 256
    int*      rank    = bsum + 256;                             // nedges
    int*      csr_src = rank + nedges;                          // nedges
    ushort_t* Wt      = (ushort_t*)(csr_src + nedges);          // 3*16384 bf16

    const int nodeBlocks = NPAD / 256;                     // 196
    const int mmBlocks   = (N_NODES + 63) / 64;            // 782
    const int fusedBlocks= (N_NODES + 15) / 16;            // 3125
    const int pgBlocks   = (N_NODES + 15) / 16;            // 3125
    const int edgeBlocks = (nedges + 255) / 256;           // 3125

    k_init<<<nodeBlocks, 256, 0, stream>>>(degi, pooled, counts);
    k_prep<<<192, 256, 0, stream>>>(W1, W2, W3, Wt);
    k_count<<<edgeBlocks, 256, 0, stream>>>(dst, degi, rank, nedges);
    k_scan1<<<nodeBlocks, 256, 0, stream>>>(degi, rowptr, bsum);
    k_scan2<<<1, 256, 0, stream>>>(bsum, nodeBlocks);
    k_scan3<<<nodeBlocks, 256, 0, stream>>>(rowptr, bsum, degi, dinv);
    k_fill<<<edgeBlocks, 256, 0, stream>>>(src, dst, rank, rowptr, csr_src, nedges);

    k_mm1<<<mmBlocks, 256, 0, stream>>>(x, Wt, dinv, (ushort_t*)TbA);
    k_fused<<<fusedBlocks, 1024, 0, stream>>>(rowptr, csr_src, dinv, TbA,
                                              Wt + 16384, b1, (ushort_t*)TbB);
    k_fused<<<fusedBlocks, 1024, 0, stream>>>(rowptr, csr_src, dinv, TbB,
                                              Wt + 32768, b2, (ushort_t*)TbA);
    k_poolgather<<<pgBlocks, 256, 0, stream>>>(rowptr, csr_src, dinv, TbA,
                                               b3, batch, pooled, counts);
    k_cls<<<NUM_GRAPHS, 128, 0, stream>>>(pooled, counts, C1, bc1, C2, bc2,
                                          (float*)d_out);
}